// Round 2
// baseline (6100.438 us; speedup 1.0000x reference)
//
#include <hip/hip_runtime.h>

#define BB 32
#define TT 512
#define DD 512
#define HH 1024
#define G4 4096   // 4*H
#define NWG 64
#define BLK 512
#define DPW 16    // h-dims per WG
#define HSLOT (BB * HH)   // one h ring slot (elements)

typedef __bf16 bf16x8 __attribute__((ext_vector_type(8)));
typedef float f32x4 __attribute__((ext_vector_type(4)));
typedef unsigned int u32x4 __attribute__((ext_vector_type(4)));
typedef unsigned short u16x4 __attribute__((ext_vector_type(4)));
typedef unsigned short u16x8 __attribute__((ext_vector_type(8)));
typedef unsigned long long u64;
typedef unsigned long long u64x2 __attribute__((ext_vector_type(2)));

__device__ __forceinline__ unsigned short f2b(float f) {
    unsigned u = __builtin_bit_cast(unsigned, f);
    u += 0x7fffu + ((u >> 16) & 1u);
    return (unsigned short)(u >> 16);
}
__device__ __forceinline__ float b2f(unsigned short s) {
    unsigned u = ((unsigned)s) << 16;
    return __builtin_bit_cast(float, u);
}

// ---------- Kernel 1: xp = bf16( X[B*T,D] @ Wi[D,4H] ), fp32 accum (unchanged) ----------
__global__ __launch_bounds__(256) void xproj_gemm(const float* __restrict__ X,
                                                  const float* __restrict__ Wi,
                                                  unsigned short* __restrict__ xp)
{
    __shared__ unsigned short As[64][40];   // [m][k]
    __shared__ unsigned short Bs[64][40];   // [n][k] transposed
    const int nb = G4 / 64;
    const int m0 = (blockIdx.x / nb) * 64;
    const int n0 = (blockIdx.x % nb) * 64;
    const int tid = threadIdx.x;
    const int w = tid >> 6;
    const int lane = tid & 63;
    const int q = lane >> 4;
    const int l16 = lane & 15;
    const int wm = (w >> 1) * 32, wn = (w & 1) * 32;

    const int ar = tid >> 2, ac = (tid & 3) * 8;
    const int bk = tid >> 3, bn = (tid & 7) * 8;

    f32x4 acc[2][2] = {};

    for (int k0 = 0; k0 < DD; k0 += 32) {
        const float* ap = X + (size_t)(m0 + ar) * DD + k0 + ac;
        float4 a0 = *(const float4*)ap;
        float4 a1 = *(const float4*)(ap + 4);
        unsigned short* as = &As[ar][ac];
        as[0]=f2b(a0.x); as[1]=f2b(a0.y); as[2]=f2b(a0.z); as[3]=f2b(a0.w);
        as[4]=f2b(a1.x); as[5]=f2b(a1.y); as[6]=f2b(a1.z); as[7]=f2b(a1.w);
        const float* bp = Wi + (size_t)(k0 + bk) * G4 + n0 + bn;
        float4 b0 = *(const float4*)bp;
        float4 b1 = *(const float4*)(bp + 4);
        Bs[bn+0][bk]=f2b(b0.x); Bs[bn+1][bk]=f2b(b0.y); Bs[bn+2][bk]=f2b(b0.z); Bs[bn+3][bk]=f2b(b0.w);
        Bs[bn+4][bk]=f2b(b1.x); Bs[bn+5][bk]=f2b(b1.y); Bs[bn+6][bk]=f2b(b1.z); Bs[bn+7][bk]=f2b(b1.w);
        __syncthreads();
        bf16x8 af0 = *(const bf16x8*)&As[wm + l16][q*8];
        bf16x8 af1 = *(const bf16x8*)&As[wm + 16 + l16][q*8];
        bf16x8 bfr0 = *(const bf16x8*)&Bs[wn + l16][q*8];
        bf16x8 bfr1 = *(const bf16x8*)&Bs[wn + 16 + l16][q*8];
        acc[0][0] = __builtin_amdgcn_mfma_f32_16x16x32_bf16(af0, bfr0, acc[0][0], 0,0,0);
        acc[0][1] = __builtin_amdgcn_mfma_f32_16x16x32_bf16(af0, bfr1, acc[0][1], 0,0,0);
        acc[1][0] = __builtin_amdgcn_mfma_f32_16x16x32_bf16(af1, bfr0, acc[1][0], 0,0,0);
        acc[1][1] = __builtin_amdgcn_mfma_f32_16x16x32_bf16(af1, bfr1, acc[1][1], 0,0,0);
        __syncthreads();
    }
    for (int i = 0; i < 2; i++) for (int j = 0; j < 2; j++) {
        int R = m0 + wm + i*16 + q*4;
        int C = n0 + wn + j*16 + l16;
        int b = R >> 9;
        int t = R & 511;
        int g = C >> 10;
        int hd = C & (HH - 1);
        u16x4 v;
        v.x = f2b(acc[i][j][0]); v.y = f2b(acc[i][j][1]);
        v.z = f2b(acc[i][j][2]); v.w = f2b(acc[i][j][3]);
        size_t off = (((size_t)(b * HH + hd) * (TT/8) + (t >> 3)) * 4 + g) * 8 + (t & 7);
        *(u16x4*)(xp + off) = v;
    }
}

// ---------- Kernel 2: persistent LSTM scan, SENTINEL DATA-POLL protocol ----------
// Baseline compute layout (8 waves: Mt batch-tile x kh K-half x cp col-pair, 32
// MFMAs/wave/step). The entire flag/counter sync chain is GONE. hbuf is poisoned
// to 0xFFFF (bf16 -NaN, unreachable: |h|<1 so f2b(h) is always finite) before
// launch. Producers fire-and-forget agent-scope u64 h-quad stores — no vmcnt
// drain, no flag publish. Consumers spin on agent-scope u64 loads of their OWN
// a-fragments until no quad is sentinel; the successful spin pass IS the MFMA
// input (no separate ha load). Barriers are raw lgkmcnt(0)+s_barrier (LDS-only,
// vmcnt never drained on the critical path). Critical path/step = one store→L3
// landing + ~half a poll period + MFMA + pointwise.
__global__ __launch_bounds__(BLK, 1) void lstm_seq(
    const unsigned short* __restrict__ xp,      // [B][H][T/8][4][8] bf16
    const int* __restrict__ lengths,
    const float* __restrict__ c0,
    const float* __restrict__ h0,
    const float* __restrict__ Wh,
    const float* __restrict__ bias,
    float* __restrict__ out,                    // outputs[B,T,H] | c_fin[B,H] | h_fin[B,H]
    unsigned short* __restrict__ hbuf)          // [T+1][B*H] bf16 ring, poisoned 0xFF
{
    __shared__ float gs[2][32][65];          // [khalf][batch][gate*16+dim]
    const int wg = blockIdx.x;
    const int tid = threadIdx.x;
    const int lane = tid & 63;
    const int w = tid >> 6;                  // 0..7
    const int q = lane >> 4, l16 = lane & 15;

    const int Mt = (w & 1) * 16;             // batch tile
    const int kh = (w >> 1) & 1;             // K half
    const int cp = w >> 2;                   // col-tile pair: ct = cp*2 + cc
    const int kbase = kh * 512;

    // ---- one-time: load this wave's 32 Wh B-fragments into registers ----
    bf16x8 breg[16][2];
    #pragma unroll
    for (int kk = 0; kk < 16; ++kk) {
        #pragma unroll
        for (int cc = 0; cc < 2; ++cc) {
            const int col = (cp*2 + cc) * HH + wg * DPW + l16;
            const int kb = kbase + kk*32 + q*8;
            u16x8 tv;
            #pragma unroll
            for (int e = 0; e < 8; ++e)
                tv[e] = f2b(Wh[(size_t)(kb + e) * G4 + col]);
            breg[kk][cc] = __builtin_bit_cast(bf16x8, tv);
        }
    }

    const int bb = tid >> 4, dd = tid & 15;  // all 512 threads do pointwise
    const int gdim = wg * DPW + dd;
    float c   = c0[bb * HH + gdim];
    const int len = lengths[bb];
    const float bi  = bias[0*HH + gdim];
    const float bfg = bias[1*HH + gdim];
    const float bgv = bias[2*HH + gdim];
    const float bo  = bias[3*HH + gdim];
    const size_t xrow = ((size_t)bb * HH + gdim) * (TT/8) * 32;

    // h0 init: 128 threads store this WG's slice (32 b x 16 dims = 128 quads).
    // No barrier needed — consumers spin on the data itself.
    if (tid < 128) {
        int b2 = tid >> 2, j = (tid & 3) * 4;
        const float* hp0 = h0 + (size_t)b2 * HH + wg * DPW + j;
        unsigned lo = (unsigned)f2b(hp0[0]) | ((unsigned)f2b(hp0[1]) << 16);
        unsigned hi = (unsigned)f2b(hp0[2]) | ((unsigned)f2b(hp0[3]) << 16);
        u64 v = (u64)lo | ((u64)hi << 32);
        __hip_atomic_store((u64*)(hbuf + (size_t)b2 * HH + wg * DPW + j), v,
                           __ATOMIC_RELAXED, __HIP_MEMORY_SCOPE_AGENT);
    }

    for (int t0 = 0; t0 < TT; t0 += 8) {
        // Prefetch 8 steps x 4 gates of x-projection: one contiguous 64B chunk.
        const unsigned short* xc = xp + xrow + (size_t)(t0 >> 3) * 32;
        u32x4 xq0 = __builtin_nontemporal_load((const u32x4*)(xc + 0));
        u32x4 xq1 = __builtin_nontemporal_load((const u32x4*)(xc + 8));
        u32x4 xq2 = __builtin_nontemporal_load((const u32x4*)(xc + 16));
        u32x4 xq3 = __builtin_nontemporal_load((const u32x4*)(xc + 24));
        float hreg[8];
        #pragma unroll
        for (int dt = 0; dt < 8; ++dt) {
            const int t = t0 + dt;
            // ---- spin until this wave's 16 a-frag chunks (32 u64 quads) are real ----
            const unsigned short* ha = hbuf + (size_t)t * HSLOT
                                     + (size_t)(Mt + l16) * HH + kbase + q*8;
            u64 alo[16], ahi[16];
            for (;;) {
                #pragma unroll
                for (int kk = 0; kk < 16; ++kk) {
                    alo[kk] = __hip_atomic_load((const u64*)(ha + kk*32),
                                                __ATOMIC_RELAXED, __HIP_MEMORY_SCOPE_AGENT);
                    ahi[kk] = __hip_atomic_load((const u64*)(ha + kk*32 + 4),
                                                __ATOMIC_RELAXED, __HIP_MEMORY_SCOPE_AGENT);
                }
                unsigned bad = 0;
                #pragma unroll
                for (int kk = 0; kk < 16; ++kk) {
                    bad |= (((unsigned)alo[kk] & 0xFFFFu) == 0xFFFFu);
                    bad |= (((unsigned)ahi[kk] & 0xFFFFu) == 0xFFFFu);
                }
                if (__all(bad == 0)) break;
            }
            // ---- MFMA directly from the spin registers ----
            f32x4 acc0 = {0.f,0.f,0.f,0.f}, acc1 = {0.f,0.f,0.f,0.f};
            #pragma unroll
            for (int kk = 0; kk < 16; ++kk) {
                u64x2 t2; t2.x = alo[kk]; t2.y = ahi[kk];
                bf16x8 a = __builtin_bit_cast(bf16x8, t2);
                acc0 = __builtin_amdgcn_mfma_f32_16x16x32_bf16(a, breg[kk][0], acc0, 0,0,0);
                acc1 = __builtin_amdgcn_mfma_f32_16x16x32_bf16(a, breg[kk][1], acc1, 0,0,0);
            }
            #pragma unroll
            for (int r = 0; r < 4; ++r) {
                gs[kh][Mt + q*4 + r][(cp*2+0)*16 + l16] = acc0[r];
                gs[kh][Mt + q*4 + r][(cp*2+1)*16 + l16] = acc1[r];
            }
            // LDS-only barrier: do NOT drain vmcnt (h stores stay in flight).
            asm volatile("s_waitcnt lgkmcnt(0)" ::: "memory");
            __builtin_amdgcn_s_barrier();
            const int wi = dt >> 1, sh = (dt & 1) * 16;
            float gi = gs[0][bb][ 0 + dd] + gs[1][bb][ 0 + dd] + b2f((unsigned short)(xq0[wi] >> sh)) + bi;
            float gf = gs[0][bb][16 + dd] + gs[1][bb][16 + dd] + b2f((unsigned short)(xq1[wi] >> sh)) + bfg;
            float gg = gs[0][bb][32 + dd] + gs[1][bb][32 + dd] + b2f((unsigned short)(xq2[wi] >> sh)) + bgv;
            float go = gs[0][bb][48 + dd] + gs[1][bb][48 + dd] + b2f((unsigned short)(xq3[wi] >> sh)) + bo;
            float si = 1.f / (1.f + __expf(-gi));
            float sf = 1.f / (1.f + __expf(-gf));
            float so = 1.f / (1.f + __expf(-go));
            float tg = 1.f - 2.f / (1.f + __expf(2.f * gg));
            c = sf * c + si * tg;
            float th = 1.f - 2.f / (1.f + __expf(2.f * c));
            float h = so * th;
            hreg[dt] = h;
            // Pack 4 bf16 h (dims 4-aligned) into u64 via shuffles; one store/quad.
            // Fire-and-forget: no drain, no flag — consumers validate the data.
            unsigned v = (unsigned)f2b(h);
            unsigned p1 = __shfl_xor(v, 1);
            unsigned pair = (dd & 1) ? (p1 | (v << 16)) : (v | (p1 << 16));
            unsigned p2 = __shfl_xor(pair, 2);
            u64 quad = (dd & 2) ? ((u64)p2 | ((u64)pair << 32))
                                : ((u64)pair | ((u64)p2 << 32));
            if ((dd & 3) == 0)
                __hip_atomic_store((u64*)(hbuf + (size_t)(t + 1) * HSLOT + (size_t)bb * HH + gdim),
                                   quad, __ATOMIC_RELAXED, __HIP_MEMORY_SCOPE_AGENT);
            if (t == len - 1) {       // rare: final states
                __builtin_nontemporal_store(c, &out[(size_t)BB*TT*HH + bb*HH + gdim]);
                __builtin_nontemporal_store(h, &out[(size_t)BB*TT*HH + (size_t)BB*HH + bb*HH + gdim]);
            }
            // LDS-only barrier: gs reads (above) done before next step's gs writes.
            asm volatile("s_waitcnt lgkmcnt(0)" ::: "memory");
            __builtin_amdgcn_s_barrier();
        }
        // Flush 8 buffered h outputs; store-acks drain off the critical path.
        #pragma unroll
        for (int j = 0; j < 8; ++j)
            __builtin_nontemporal_store(hreg[j], &out[((size_t)bb * TT + t0 + j) * HH + gdim]);
    }
}

extern "C" void kernel_launch(void* const* d_in, const int* in_sizes, int n_in,
                              void* d_out, int out_size, void* d_ws, size_t ws_size,
                              hipStream_t stream)
{
    const float* X    = (const float*)d_in[0];
    const int*   lens = (const int*)d_in[1];
    const float* c0   = (const float*)d_in[2];
    const float* h0   = (const float*)d_in[3];
    const float* Wi   = (const float*)d_in[4];
    const float* Wh   = (const float*)d_in[5];
    const float* bias = (const float*)d_in[6];
    float* out = (float*)d_out;

    // ws layout: xp bf16 [B][H][T/8][4][8] (134.2 MB) | hbuf ring bf16 [T+1][B*H]
    //            (33.6 MB, poisoned to 0xFFFF each launch)
    unsigned short* xp   = (unsigned short*)d_ws;
    unsigned short* hbuf = xp + (size_t)BB * HH * TT * 4;

    // Re-poison the full ring every launch (sentinel protocol requirement).
    (void)hipMemsetAsync(hbuf, 0xff, (size_t)(TT + 1) * HSLOT * sizeof(unsigned short), stream);

    xproj_gemm<<<dim3((BB*TT/64) * (G4/64)), dim3(256), 0, stream>>>(X, Wi, xp);

    const unsigned short* xp_c = xp;
    unsigned short* hbuf_p = hbuf;
    void* args[8];
    args[0] = (void*)&xp_c;
    args[1] = (void*)&lens;
    args[2] = (void*)&c0;
    args[3] = (void*)&h0;
    args[4] = (void*)&Wh;
    args[5] = (void*)&bias;
    args[6] = (void*)&out;
    args[7] = (void*)&hbuf_p;
    (void)hipLaunchCooperativeKernel((void*)lstm_seq, dim3(NWG), dim3(BLK), args, 0, stream);
}

// Round 3
// 5308.993 us; speedup vs baseline: 1.1491x; 1.1491x over previous
//
#include <hip/hip_runtime.h>

#define BB 32
#define TT 512
#define DD 512
#define HH 1024
#define G4 4096   // 4*H
#define NWG 64
#define BLK 512
#define DPW 16    // h-dims per WG
#define HSLOT (BB * HH)   // one h ring slot (elements)
#define FSTRIDE 64        // flag padding: one flag per 256B line

typedef __bf16 bf16x8 __attribute__((ext_vector_type(8)));
typedef float f32x4 __attribute__((ext_vector_type(4)));
typedef unsigned int u32x4 __attribute__((ext_vector_type(4)));
typedef unsigned short u16x4 __attribute__((ext_vector_type(4)));
typedef unsigned short u16x8 __attribute__((ext_vector_type(8)));
typedef unsigned long long u64;
typedef unsigned long long u64x2 __attribute__((ext_vector_type(2)));

__device__ __forceinline__ unsigned short f2b(float f) {
    unsigned u = __builtin_bit_cast(unsigned, f);
    u += 0x7fffu + ((u >> 16) & 1u);
    return (unsigned short)(u >> 16);
}
__device__ __forceinline__ float b2f(unsigned short s) {
    unsigned u = ((unsigned)s) << 16;
    return __builtin_bit_cast(float, u);
}

// ---------- Kernel 1: xp = bf16( X[B*T,D] @ Wi[D,4H] ), fp32 accum (unchanged) ----------
__global__ __launch_bounds__(256) void xproj_gemm(const float* __restrict__ X,
                                                  const float* __restrict__ Wi,
                                                  unsigned short* __restrict__ xp)
{
    __shared__ unsigned short As[64][40];   // [m][k]
    __shared__ unsigned short Bs[64][40];   // [n][k] transposed
    const int nb = G4 / 64;
    const int m0 = (blockIdx.x / nb) * 64;
    const int n0 = (blockIdx.x % nb) * 64;
    const int tid = threadIdx.x;
    const int w = tid >> 6;
    const int lane = tid & 63;
    const int q = lane >> 4;
    const int l16 = lane & 15;
    const int wm = (w >> 1) * 32, wn = (w & 1) * 32;

    const int ar = tid >> 2, ac = (tid & 3) * 8;
    const int bk = tid >> 3, bn = (tid & 7) * 8;

    f32x4 acc[2][2] = {};

    for (int k0 = 0; k0 < DD; k0 += 32) {
        const float* ap = X + (size_t)(m0 + ar) * DD + k0 + ac;
        float4 a0 = *(const float4*)ap;
        float4 a1 = *(const float4*)(ap + 4);
        unsigned short* as = &As[ar][ac];
        as[0]=f2b(a0.x); as[1]=f2b(a0.y); as[2]=f2b(a0.z); as[3]=f2b(a0.w);
        as[4]=f2b(a1.x); as[5]=f2b(a1.y); as[6]=f2b(a1.z); as[7]=f2b(a1.w);
        const float* bp = Wi + (size_t)(k0 + bk) * G4 + n0 + bn;
        float4 b0 = *(const float4*)bp;
        float4 b1 = *(const float4*)(bp + 4);
        Bs[bn+0][bk]=f2b(b0.x); Bs[bn+1][bk]=f2b(b0.y); Bs[bn+2][bk]=f2b(b0.z); Bs[bn+3][bk]=f2b(b0.w);
        Bs[bn+4][bk]=f2b(b1.x); Bs[bn+5][bk]=f2b(b1.y); Bs[bn+6][bk]=f2b(b1.z); Bs[bn+7][bk]=f2b(b1.w);
        __syncthreads();
        bf16x8 af0 = *(const bf16x8*)&As[wm + l16][q*8];
        bf16x8 af1 = *(const bf16x8*)&As[wm + 16 + l16][q*8];
        bf16x8 bfr0 = *(const bf16x8*)&Bs[wn + l16][q*8];
        bf16x8 bfr1 = *(const bf16x8*)&Bs[wn + 16 + l16][q*8];
        acc[0][0] = __builtin_amdgcn_mfma_f32_16x16x32_bf16(af0, bfr0, acc[0][0], 0,0,0);
        acc[0][1] = __builtin_amdgcn_mfma_f32_16x16x32_bf16(af0, bfr1, acc[0][1], 0,0,0);
        acc[1][0] = __builtin_amdgcn_mfma_f32_16x16x32_bf16(af1, bfr0, acc[1][0], 0,0,0);
        acc[1][1] = __builtin_amdgcn_mfma_f32_16x16x32_bf16(af1, bfr1, acc[1][1], 0,0,0);
        __syncthreads();
    }
    for (int i = 0; i < 2; i++) for (int j = 0; j < 2; j++) {
        int R = m0 + wm + i*16 + q*4;
        int C = n0 + wn + j*16 + l16;
        int b = R >> 9;
        int t = R & 511;
        int g = C >> 10;
        int hd = C & (HH - 1);
        u16x4 v;
        v.x = f2b(acc[i][j][0]); v.y = f2b(acc[i][j][1]);
        v.z = f2b(acc[i][j][2]); v.w = f2b(acc[i][j][3]);
        size_t off = (((size_t)(b * HH + hd) * (TT/8) + (t >> 3)) * 4 + g) * 8 + (t & 7);
        *(u16x4*)(xp + off) = v;
    }
}

// ---------- Kernel 2: persistent LSTM scan, PADDED-FLAG canary protocol ----------
// R0/R1/R2 triangulated the bottleneck: same-line reader/writer contention on the
// sync word(s), not round-trip latency. Fixes here:
//  * one flag per WG, each on its OWN 256B line (no line ping-pong: 1 writer/line,
//    readers gather 64 DISTINCT lines with one pipelined 64-lane load)
//  * producer publish = plain agent store after vmcnt(0) drain (no RMW convoy)
//  * consumers load h once after the flag flips (agent u64 loads, no spinning)
//  * all barriers lgkm-only; the ONLY vmcnt drain is the pre-flag h-store ack
//  * out-flush AFTER the flag store: HBM acks drain during the next poll
__global__ __launch_bounds__(BLK, 1) void lstm_seq(
    const unsigned short* __restrict__ xp,      // [B][H][T/8][4][8] bf16
    const int* __restrict__ lengths,
    const float* __restrict__ c0,
    const float* __restrict__ h0,
    const float* __restrict__ Wh,
    const float* __restrict__ bias,
    float* __restrict__ out,                    // outputs[B,T,H] | c_fin[B,H] | h_fin[B,H]
    unsigned short* __restrict__ hbuf,          // [T+1][B*H] bf16 ring
    int* __restrict__ flags)                    // [64*FSTRIDE], host memset 0xff (=-1)
{
    __shared__ float gs[2][32][65];          // [khalf][batch][gate*16+dim]
    const int wg = blockIdx.x;
    const int tid = threadIdx.x;
    const int lane = tid & 63;
    const int w = tid >> 6;                  // 0..7
    const int q = lane >> 4, l16 = lane & 15;

    const int Mt = (w & 1) * 16;             // batch tile
    const int kh = (w >> 1) & 1;             // K half
    const int cp = w >> 2;                   // col-tile pair: ct = cp*2 + cc
    const int kbase = kh * 512;

    // ---- one-time: load this wave's 32 Wh B-fragments into registers ----
    bf16x8 breg[16][2];
    #pragma unroll
    for (int kk = 0; kk < 16; ++kk) {
        #pragma unroll
        for (int cc = 0; cc < 2; ++cc) {
            const int col = (cp*2 + cc) * HH + wg * DPW + l16;
            const int kb = kbase + kk*32 + q*8;
            u16x8 tv;
            #pragma unroll
            for (int e = 0; e < 8; ++e)
                tv[e] = f2b(Wh[(size_t)(kb + e) * G4 + col]);
            breg[kk][cc] = __builtin_bit_cast(bf16x8, tv);
        }
    }

    const int bb = tid >> 4, dd = tid & 15;  // all 512 threads do pointwise
    const int gdim = wg * DPW + dd;
    float c   = c0[bb * HH + gdim];
    const int len = lengths[bb];
    const float bi  = bias[0*HH + gdim];
    const float bfg = bias[1*HH + gdim];
    const float bgv = bias[2*HH + gdim];
    const float bo  = bias[3*HH + gdim];
    const size_t xrow = ((size_t)bb * HH + gdim) * (TT/8) * 32;

    // h0 init: 128 threads store this WG's slice (32 b x 16 dims = 128 quads).
    if (tid < 128) {
        int b2 = tid >> 2, j = (tid & 3) * 4;
        const float* hp0 = h0 + (size_t)b2 * HH + wg * DPW + j;
        unsigned lo = (unsigned)f2b(hp0[0]) | ((unsigned)f2b(hp0[1]) << 16);
        unsigned hi = (unsigned)f2b(hp0[2]) | ((unsigned)f2b(hp0[3]) << 16);
        u64 v = (u64)lo | ((u64)hi << 32);
        __hip_atomic_store((u64*)(hbuf + (size_t)b2 * HH + wg * DPW + j), v,
                           __ATOMIC_RELAXED, __HIP_MEMORY_SCOPE_AGENT);
    }
    asm volatile("s_waitcnt vmcnt(0)" ::: "memory");   // h0 stores acked at L3
    __builtin_amdgcn_s_barrier();
    if (tid == 0)        // publish slot 0 (flags were -1: nobody can pass t=0 early)
        __hip_atomic_store(&flags[wg * FSTRIDE], 0, __ATOMIC_RELAXED, __HIP_MEMORY_SCOPE_AGENT);

    int fv = -1;         // wave0 per-lane cached flag value (flag of WG 'lane')
    for (int t0 = 0; t0 < TT; t0 += 8) {
        // Prefetch 8 steps x 4 gates of x-projection: one contiguous 64B chunk.
        const unsigned short* xc = xp + xrow + (size_t)(t0 >> 3) * 32;
        u32x4 xq0 = __builtin_nontemporal_load((const u32x4*)(xc + 0));
        u32x4 xq1 = __builtin_nontemporal_load((const u32x4*)(xc + 8));
        u32x4 xq2 = __builtin_nontemporal_load((const u32x4*)(xc + 16));
        u32x4 xq3 = __builtin_nontemporal_load((const u32x4*)(xc + 24));
        float hreg[8];
        #pragma unroll
        for (int dt = 0; dt < 8; ++dt) {
            const int t = t0 + dt;
            // ---- poll: 64 flags on 64 DISTINCT lines, one wave-wide gather ----
            if (w == 0) {
                while (!__all(fv >= t))
                    fv = __hip_atomic_load(&flags[lane * FSTRIDE],
                                           __ATOMIC_RELAXED, __HIP_MEMORY_SCOPE_AGENT);
            }
            __builtin_amdgcn_s_barrier();                               // b1 (also protects gs)
            // ---- load h slot t (agent u64 pairs, single-shot) + MFMA ----
            const unsigned short* ha = hbuf + (size_t)t * HSLOT
                                     + (size_t)(Mt + l16) * HH + kbase + q*8;
            f32x4 acc0 = {0.f,0.f,0.f,0.f}, acc1 = {0.f,0.f,0.f,0.f};
            #pragma unroll
            for (int kk = 0; kk < 16; ++kk) {
                u64 alo = __hip_atomic_load((const u64*)(ha + kk*32),
                                            __ATOMIC_RELAXED, __HIP_MEMORY_SCOPE_AGENT);
                u64 ahi = __hip_atomic_load((const u64*)(ha + kk*32 + 4),
                                            __ATOMIC_RELAXED, __HIP_MEMORY_SCOPE_AGENT);
                u64x2 t2; t2.x = alo; t2.y = ahi;
                bf16x8 a = __builtin_bit_cast(bf16x8, t2);
                acc0 = __builtin_amdgcn_mfma_f32_16x16x32_bf16(a, breg[kk][0], acc0, 0,0,0);
                acc1 = __builtin_amdgcn_mfma_f32_16x16x32_bf16(a, breg[kk][1], acc1, 0,0,0);
            }
            #pragma unroll
            for (int r = 0; r < 4; ++r) {
                gs[kh][Mt + q*4 + r][(cp*2+0)*16 + l16] = acc0[r];
                gs[kh][Mt + q*4 + r][(cp*2+1)*16 + l16] = acc1[r];
            }
            asm volatile("s_waitcnt lgkmcnt(0)" ::: "memory");          // LDS-only
            __builtin_amdgcn_s_barrier();                               // b2
            // ---- pointwise (all 512 threads) ----
            const int wi = dt >> 1, sh = (dt & 1) * 16;
            float gi = gs[0][bb][ 0 + dd] + gs[1][bb][ 0 + dd] + b2f((unsigned short)(xq0[wi] >> sh)) + bi;
            float gf = gs[0][bb][16 + dd] + gs[1][bb][16 + dd] + b2f((unsigned short)(xq1[wi] >> sh)) + bfg;
            float gg = gs[0][bb][32 + dd] + gs[1][bb][32 + dd] + b2f((unsigned short)(xq2[wi] >> sh)) + bgv;
            float go = gs[0][bb][48 + dd] + gs[1][bb][48 + dd] + b2f((unsigned short)(xq3[wi] >> sh)) + bo;
            float si = 1.f / (1.f + __expf(-gi));
            float sf = 1.f / (1.f + __expf(-gf));
            float so = 1.f / (1.f + __expf(-go));
            float tg = 1.f - 2.f / (1.f + __expf(2.f * gg));
            c = sf * c + si * tg;
            float th = 1.f - 2.f / (1.f + __expf(2.f * c));
            float h = so * th;
            hreg[dt] = h;
            // Pack 4 bf16 h (dims 4-aligned) into u64 via shuffles; one store/quad.
            unsigned v = (unsigned)f2b(h);
            unsigned p1 = __shfl_xor(v, 1);
            unsigned pair = (dd & 1) ? (p1 | (v << 16)) : (v | (p1 << 16));
            unsigned p2 = __shfl_xor(pair, 2);
            u64 quad = (dd & 2) ? ((u64)p2 | ((u64)pair << 32))
                                : ((u64)pair | ((u64)p2 << 32));
            if ((dd & 3) == 0)
                __hip_atomic_store((u64*)(hbuf + (size_t)(t + 1) * HSLOT + (size_t)bb * HH + gdim),
                                   quad, __ATOMIC_RELAXED, __HIP_MEMORY_SCOPE_AGENT);
            if (t == len - 1) {       // rare: final states
                __builtin_nontemporal_store(c, &out[(size_t)BB*TT*HH + bb*HH + gdim]);
                __builtin_nontemporal_store(h, &out[(size_t)BB*TT*HH + (size_t)BB*HH + bb*HH + gdim]);
            }
            // ---- canary: ack h stores, then publish this WG's flag ----
            asm volatile("s_waitcnt vmcnt(0)" ::: "memory");            // ~L3 ack, only drain/step
            __builtin_amdgcn_s_barrier();                               // b3: all waves acked
            if (tid == 0)
                __hip_atomic_store(&flags[wg * FSTRIDE], t + 1,
                                   __ATOMIC_RELAXED, __HIP_MEMORY_SCOPE_AGENT);
            if (dt == 7) {
                // Flush 8 buffered h outputs AFTER the flag: HBM acks drain
                // during the next poll, off the critical path.
                #pragma unroll
                for (int j = 0; j < 8; ++j)
                    __builtin_nontemporal_store(hreg[j], &out[((size_t)bb * TT + t0 + j) * HH + gdim]);
            }
        }
    }
}

extern "C" void kernel_launch(void* const* d_in, const int* in_sizes, int n_in,
                              void* d_out, int out_size, void* d_ws, size_t ws_size,
                              hipStream_t stream)
{
    const float* X    = (const float*)d_in[0];
    const int*   lens = (const int*)d_in[1];
    const float* c0   = (const float*)d_in[2];
    const float* h0   = (const float*)d_in[3];
    const float* Wi   = (const float*)d_in[4];
    const float* Wh   = (const float*)d_in[5];
    const float* bias = (const float*)d_in[6];
    float* out = (float*)d_out;

    // ws layout: xp bf16 [B][H][T/8][4][8] (134.2 MB) | hbuf ring bf16 [T+1][B*H]
    //            (33.6 MB) | flags int[64*FSTRIDE] (16 KB, one per 256B line)
    unsigned short* xp   = (unsigned short*)d_ws;
    unsigned short* hbuf = xp + (size_t)BB * HH * TT * 4;
    int*            flags = (int*)(hbuf + (size_t)(TT + 1) * HSLOT);

    // flags = -1: nobody passes the t=0 poll until h0 is published.
    (void)hipMemsetAsync(flags, 0xff, sizeof(int) * NWG * FSTRIDE, stream);

    xproj_gemm<<<dim3((BB*TT/64) * (G4/64)), dim3(256), 0, stream>>>(X, Wi, xp);

    const unsigned short* xp_c = xp;
    unsigned short* hbuf_p = hbuf;
    int* flags_p = flags;
    void* args[9];
    args[0] = (void*)&xp_c;
    args[1] = (void*)&lens;
    args[2] = (void*)&c0;
    args[3] = (void*)&h0;
    args[4] = (void*)&Wh;
    args[5] = (void*)&bias;
    args[6] = (void*)&out;
    args[7] = (void*)&hbuf_p;
    args[8] = (void*)&flags_p;
    (void)hipLaunchCooperativeKernel((void*)lstm_seq, dim3(NWG), dim3(BLK), args, 0, stream);
}

// Round 8
// 3609.116 us; speedup vs baseline: 1.6903x; 1.4710x over previous
//
#include <hip/hip_runtime.h>

#define BB 32
#define TT 512
#define DD 512
#define HH 1024
#define G4 4096   // 4*H
#define NWG 64
#define BLK 512
#define DPW 16    // h-dims per WG
#define HSLOT (BB * HH)   // one h ring slot (elements)
#define FSTR 32           // flag stride in ints = 128B line per WG

typedef __bf16 bf16x8 __attribute__((ext_vector_type(8)));
typedef float f32x4 __attribute__((ext_vector_type(4)));
typedef unsigned int u32x4 __attribute__((ext_vector_type(4)));
typedef unsigned short u16x4 __attribute__((ext_vector_type(4)));
typedef unsigned short u16x8 __attribute__((ext_vector_type(8)));
typedef unsigned long long u64;

__device__ __forceinline__ unsigned short f2b(float f) {
    unsigned u = __builtin_bit_cast(unsigned, f);
    u += 0x7fffu + ((u >> 16) & 1u);
    return (unsigned short)(u >> 16);
}
__device__ __forceinline__ float b2f(unsigned short s) {
    unsigned u = ((unsigned)s) << 16;
    return __builtin_bit_cast(float, u);
}

// ---------- Kernel 1: xp = bf16( X[B*T,D] @ Wi[D,4H] ), fp32 accum (unchanged) ----------
__global__ __launch_bounds__(256) void xproj_gemm(const float* __restrict__ X,
                                                  const float* __restrict__ Wi,
                                                  unsigned short* __restrict__ xp)
{
    __shared__ unsigned short As[64][40];   // [m][k]
    __shared__ unsigned short Bs[64][40];   // [n][k] transposed
    const int nb = G4 / 64;
    const int m0 = (blockIdx.x / nb) * 64;
    const int n0 = (blockIdx.x % nb) * 64;
    const int tid = threadIdx.x;
    const int w = tid >> 6;
    const int lane = tid & 63;
    const int q = lane >> 4;
    const int l16 = lane & 15;
    const int wm = (w >> 1) * 32, wn = (w & 1) * 32;

    const int ar = tid >> 2, ac = (tid & 3) * 8;
    const int bk = tid >> 3, bn = (tid & 7) * 8;

    f32x4 acc[2][2] = {};

    for (int k0 = 0; k0 < DD; k0 += 32) {
        const float* ap = X + (size_t)(m0 + ar) * DD + k0 + ac;
        float4 a0 = *(const float4*)ap;
        float4 a1 = *(const float4*)(ap + 4);
        unsigned short* as = &As[ar][ac];
        as[0]=f2b(a0.x); as[1]=f2b(a0.y); as[2]=f2b(a0.z); as[3]=f2b(a0.w);
        as[4]=f2b(a1.x); as[5]=f2b(a1.y); as[6]=f2b(a1.z); as[7]=f2b(a1.w);
        const float* bp = Wi + (size_t)(k0 + bk) * G4 + n0 + bn;
        float4 b0 = *(const float4*)bp;
        float4 b1 = *(const float4*)(bp + 4);
        Bs[bn+0][bk]=f2b(b0.x); Bs[bn+1][bk]=f2b(b0.y); Bs[bn+2][bk]=f2b(b0.z); Bs[bn+3][bk]=f2b(b0.w);
        Bs[bn+4][bk]=f2b(b1.x); Bs[bn+5][bk]=f2b(b1.y); Bs[bn+6][bk]=f2b(b1.z); Bs[bn+7][bk]=f2b(b1.w);
        __syncthreads();
        bf16x8 af0 = *(const bf16x8*)&As[wm + l16][q*8];
        bf16x8 af1 = *(const bf16x8*)&As[wm + 16 + l16][q*8];
        bf16x8 bfr0 = *(const bf16x8*)&Bs[wn + l16][q*8];
        bf16x8 bfr1 = *(const bf16x8*)&Bs[wn + 16 + l16][q*8];
        acc[0][0] = __builtin_amdgcn_mfma_f32_16x16x32_bf16(af0, bfr0, acc[0][0], 0,0,0);
        acc[0][1] = __builtin_amdgcn_mfma_f32_16x16x32_bf16(af0, bfr1, acc[0][1], 0,0,0);
        acc[1][0] = __builtin_amdgcn_mfma_f32_16x16x32_bf16(af1, bfr0, acc[1][0], 0,0,0);
        acc[1][1] = __builtin_amdgcn_mfma_f32_16x16x32_bf16(af1, bfr1, acc[1][1], 0,0,0);
        __syncthreads();
    }
    for (int i = 0; i < 2; i++) for (int j = 0; j < 2; j++) {
        int R = m0 + wm + i*16 + q*4;
        int C = n0 + wn + j*16 + l16;
        int b = R >> 9;
        int t = R & 511;
        int g = C >> 10;
        int hd = C & (HH - 1);
        u16x4 v;
        v.x = f2b(acc[i][j][0]); v.y = f2b(acc[i][j][1]);
        v.z = f2b(acc[i][j][2]); v.w = f2b(acc[i][j][3]);
        size_t off = (((size_t)(b * HH + hd) * (TT/8) + (t >> 3)) * 4 + g) * 8 + (t & 7);
        *(u16x4*)(xp + off) = v;
    }
}

// ---------- Kernel 2: persistent LSTM scan, AGGREGATOR-EPOCH protocol ----------
// Scoreboard R0-R3: protocol cost tracks LINE CONTENTION + POLL WIDTH, not
// latency. R0 (6.2us/step): one line carries 64 RMWs AND 64 pollers. R1
// (4.76/round): plain flag stores + narrow poll = fastest. R3 (9.5): 64 WGs
// each polling 64 distinct lines = MALL poll-storm. This round uses the
// contention-minimal topology, with R0's PROVEN compute core + memory
// semantics (__hip_atomic AGENT ops, plain cached loads of write-once slots):
//   * producers: tid0 plain atomic store to OWN 128B flag line (write-only)
//   * ONE aggregator (WG0 wave0): the only wide reader; gathers 64 flags,
//     publishes a single EPOCH word
//   * consumers: tid0 polls the ONE epoch line (read-only broadcast, 1 writer)
// Bounded spins everywhere: free-run on expiry = loud failure, never a hang.
__global__ __launch_bounds__(BLK, 1) void lstm_seq(
    const unsigned short* __restrict__ xp,      // [B][H][T/8][4][8] bf16
    const int* __restrict__ lengths,
    const float* __restrict__ c0,
    const float* __restrict__ h0,
    const float* __restrict__ Wh,
    const float* __restrict__ bias,
    float* __restrict__ out,                    // outputs[B,T,H] | c_fin[B,H] | h_fin[B,H]
    unsigned short* __restrict__ hbuf,          // [T+1][B*H] bf16 ring
    int* __restrict__ flags,                    // [NWG*FSTR] per-WG flags, memset 0xff
    int* __restrict__ epoch)                    // single word, memset 0xff (=-1)
{
    __shared__ float gs[2][32][65];          // [khalf][batch][gate*16+dim]
    const int wg = blockIdx.x;
    const int tid = threadIdx.x;
    const int lane = tid & 63;
    const int w = tid >> 6;                  // 0..7
    const int q = lane >> 4, l16 = lane & 15;

    const int Mt = (w & 1) * 16;             // batch tile
    const int kh = (w >> 1) & 1;             // K half
    const int cp = w >> 2;                   // col-tile pair: ct = cp*2 + cc
    const int kbase = kh * 512;

    // ---- one-time: load this wave's 32 Wh B-fragments into registers ----
    bf16x8 breg[16][2];
    #pragma unroll
    for (int kk = 0; kk < 16; ++kk) {
        #pragma unroll
        for (int cc = 0; cc < 2; ++cc) {
            const int col = (cp*2 + cc) * HH + wg * DPW + l16;
            const int kb = kbase + kk*32 + q*8;
            u16x8 tv;
            #pragma unroll
            for (int e = 0; e < 8; ++e)
                tv[e] = f2b(Wh[(size_t)(kb + e) * G4 + col]);
            breg[kk][cc] = __builtin_bit_cast(bf16x8, tv);
        }
    }

    const int bb = tid >> 4, dd = tid & 15;  // all 512 threads do pointwise
    const int gdim = wg * DPW + dd;
    float c   = c0[bb * HH + gdim];
    const int len = lengths[bb];
    const float bi  = bias[0*HH + gdim];
    const float bfg = bias[1*HH + gdim];
    const float bgv = bias[2*HH + gdim];
    const float bo  = bias[3*HH + gdim];
    const size_t xrow = ((size_t)bb * HH + gdim) * (TT/8) * 32;

    // h0 init: 128 threads store this WG's slice (32 b x 16 dims = 128 quads).
    if (tid < 128) {
        int b2 = tid >> 2, j = (tid & 3) * 4;
        const float* hp0 = h0 + (size_t)b2 * HH + wg * DPW + j;
        unsigned lo = (unsigned)f2b(hp0[0]) | ((unsigned)f2b(hp0[1]) << 16);
        unsigned hi = (unsigned)f2b(hp0[2]) | ((unsigned)f2b(hp0[3]) << 16);
        u64 v = (u64)lo | ((u64)hi << 32);
        __hip_atomic_store((u64*)(hbuf + (size_t)b2 * HH + wg * DPW + j), v,
                           __ATOMIC_RELAXED, __HIP_MEMORY_SCOPE_AGENT);
    }
    __syncthreads();                  // vmcnt(0): init stores acked at coherence point
    if (tid == 0)                     // publish own flag (write-only line)
        __hip_atomic_store(&flags[wg * FSTR], 0, __ATOMIC_RELAXED, __HIP_MEMORY_SCOPE_AGENT);

    int fv = -1;                      // WG0 wave0: per-lane cached flag of WG 'lane'
    if (wg == 0 && w == 0) {          // aggregate slot 0 -> epoch
        int spins = 0;
        while (!__all(fv >= 0)) {
            fv = __hip_atomic_load(&flags[lane * FSTR], __ATOMIC_RELAXED, __HIP_MEMORY_SCOPE_AGENT);
            if (++spins > (1 << 20)) break;
        }
        if (lane == 0)
            __hip_atomic_store(epoch, 0, __ATOMIC_RELAXED, __HIP_MEMORY_SCOPE_AGENT);
    }

    for (int t0 = 0; t0 < TT; t0 += 8) {
        // Prefetch 8 steps x 4 gates of x-projection: one contiguous 64B chunk.
        const unsigned short* xc = xp + xrow + (size_t)(t0 >> 3) * 32;
        u32x4 xq0 = __builtin_nontemporal_load((const u32x4*)(xc + 0));
        u32x4 xq1 = __builtin_nontemporal_load((const u32x4*)(xc + 8));
        u32x4 xq2 = __builtin_nontemporal_load((const u32x4*)(xc + 16));
        u32x4 xq3 = __builtin_nontemporal_load((const u32x4*)(xc + 24));
        float hreg[8];
        #pragma unroll
        for (int dt = 0; dt < 8; ++dt) {
            const int t = t0 + dt;
            // ---- poll the single epoch line (read-only broadcast, 1 writer/step) ----
            if (tid == 0) {
                int spins = 0;
                while (__hip_atomic_load(epoch, __ATOMIC_RELAXED,
                                         __HIP_MEMORY_SCOPE_AGENT) < t) {
                    if (++spins > (1 << 20)) break;
                }
            }
            __syncthreads();                                            // b1
            // ---- h slot t: plain cached loads (write-once slots; R0-proven) + MFMA ----
            const unsigned short* ha = hbuf + (size_t)t * HSLOT
                                     + (size_t)(Mt + l16) * HH + kbase + q*8;
            f32x4 acc0 = {0.f,0.f,0.f,0.f}, acc1 = {0.f,0.f,0.f,0.f};
            #pragma unroll
            for (int kk = 0; kk < 16; ++kk) {
                bf16x8 a = *(const bf16x8*)(ha + kk*32);
                acc0 = __builtin_amdgcn_mfma_f32_16x16x32_bf16(a, breg[kk][0], acc0, 0,0,0);
                acc1 = __builtin_amdgcn_mfma_f32_16x16x32_bf16(a, breg[kk][1], acc1, 0,0,0);
            }
            #pragma unroll
            for (int r = 0; r < 4; ++r) {
                gs[kh][Mt + q*4 + r][(cp*2+0)*16 + l16] = acc0[r];
                gs[kh][Mt + q*4 + r][(cp*2+1)*16 + l16] = acc1[r];
            }
            __syncthreads();                                            // b2
            // ---- pointwise (all 512 threads) ----
            const int wi = dt >> 1, sh = (dt & 1) * 16;
            float gi = gs[0][bb][ 0 + dd] + gs[1][bb][ 0 + dd] + b2f((unsigned short)(xq0[wi] >> sh)) + bi;
            float gf = gs[0][bb][16 + dd] + gs[1][bb][16 + dd] + b2f((unsigned short)(xq1[wi] >> sh)) + bfg;
            float gg = gs[0][bb][32 + dd] + gs[1][bb][32 + dd] + b2f((unsigned short)(xq2[wi] >> sh)) + bgv;
            float go = gs[0][bb][48 + dd] + gs[1][bb][48 + dd] + b2f((unsigned short)(xq3[wi] >> sh)) + bo;
            float si = 1.f / (1.f + __expf(-gi));
            float sf = 1.f / (1.f + __expf(-gf));
            float so = 1.f / (1.f + __expf(-go));
            float tg = 1.f - 2.f / (1.f + __expf(2.f * gg));
            c = sf * c + si * tg;
            float th = 1.f - 2.f / (1.f + __expf(2.f * c));
            float h = so * th;
            hreg[dt] = h;
            // Pack 4 bf16 h (dims 4-aligned) into u64 via shuffles; one store/quad.
            unsigned v = (unsigned)f2b(h);
            unsigned p1 = __shfl_xor(v, 1);
            unsigned pair = (dd & 1) ? (p1 | (v << 16)) : (v | (p1 << 16));
            unsigned p2 = __shfl_xor(pair, 2);
            u64 quad = (dd & 2) ? ((u64)p2 | ((u64)pair << 32))
                                : ((u64)pair | ((u64)p2 << 32));
            if ((dd & 3) == 0)
                __hip_atomic_store((u64*)(hbuf + (size_t)(t + 1) * HSLOT + (size_t)bb * HH + gdim),
                                   quad, __ATOMIC_RELAXED, __HIP_MEMORY_SCOPE_AGENT);
            if (t == len - 1) {       // rare: final states
                __builtin_nontemporal_store(c, &out[(size_t)BB*TT*HH + bb*HH + gdim]);
                __builtin_nontemporal_store(h, &out[(size_t)BB*TT*HH + (size_t)BB*HH + bb*HH + gdim]);
            }
            __syncthreads();          // b3: vmcnt(0) — h stores acked at coherence point
            if (tid == 0)             // publish own flag (plain store, own line, no RMW)
                __hip_atomic_store(&flags[wg * FSTR], t + 1,
                                   __ATOMIC_RELAXED, __HIP_MEMORY_SCOPE_AGENT);
            if (wg == 0 && w == 0) {  // SOLE wide reader: gather 64 flags -> epoch
                int spins = 0;
                while (!__all(fv >= t + 1)) {
                    fv = __hip_atomic_load(&flags[lane * FSTR],
                                           __ATOMIC_RELAXED, __HIP_MEMORY_SCOPE_AGENT);
                    if (++spins > (1 << 20)) break;
                }
                if (lane == 0)
                    __hip_atomic_store(epoch, t + 1, __ATOMIC_RELAXED, __HIP_MEMORY_SCOPE_AGENT);
            }
        }
        // Flush 8 buffered h outputs; store-acks drain under the next poll wait.
        #pragma unroll
        for (int j = 0; j < 8; ++j)
            __builtin_nontemporal_store(hreg[j], &out[((size_t)bb * TT + t0 + j) * HH + gdim]);
    }
}

extern "C" void kernel_launch(void* const* d_in, const int* in_sizes, int n_in,
                              void* d_out, int out_size, void* d_ws, size_t ws_size,
                              hipStream_t stream)
{
    const float* X    = (const float*)d_in[0];
    const int*   lens = (const int*)d_in[1];
    const float* c0   = (const float*)d_in[2];
    const float* h0   = (const float*)d_in[3];
    const float* Wi   = (const float*)d_in[4];
    const float* Wh   = (const float*)d_in[5];
    const float* bias = (const float*)d_in[6];
    float* out = (float*)d_out;

    // ws layout: xp bf16 [B][H][T/8][4][8] (134.2 MB) | hbuf ring bf16 [T+1][B*H]
    //            (33.6 MB) | flags int[NWG*FSTR] (8 KB) | epoch int (+pad)
    unsigned short* xp   = (unsigned short*)d_ws;
    unsigned short* hbuf = xp + (size_t)BB * HH * TT * 4;
    int* flags = (int*)(hbuf + (size_t)(TT + 1) * HSLOT);
    int* epoch = flags + NWG * FSTR;

    // flags and epoch = -1: nobody passes t=0 until h0 published + aggregated.
    (void)hipMemsetAsync(flags, 0xff, sizeof(int) * (NWG * FSTR + 64), stream);

    xproj_gemm<<<dim3((BB*TT/64) * (G4/64)), dim3(256), 0, stream>>>(X, Wi, xp);

    const unsigned short* xp_c = xp;
    unsigned short* hbuf_p = hbuf;
    int* flags_p = flags;
    int* epoch_p = epoch;
    void* args[10];
    args[0] = (void*)&xp_c;
    args[1] = (void*)&lens;
    args[2] = (void*)&c0;
    args[3] = (void*)&h0;
    args[4] = (void*)&Wh;
    args[5] = (void*)&bias;
    args[6] = (void*)&out;
    args[7] = (void*)&hbuf_p;
    args[8] = (void*)&flags_p;
    args[9] = (void*)&epoch_p;
    (void)hipLaunchCooperativeKernel((void*)lstm_seq, dim3(NWG), dim3(BLK), args, 0, stream);
}

// Round 10
// 3515.648 us; speedup vs baseline: 1.7352x; 1.0266x over previous
//
#include <hip/hip_runtime.h>

#define BB 32
#define TT 512
#define DD 512
#define HH 1024
#define G4 4096   // 4*H
#define NWG 64
#define BLK 512
#define DPW 16    // h-dims per WG
#define HSLOT (BB * HH)   // one h ring slot (elements)

typedef __bf16 bf16x8 __attribute__((ext_vector_type(8)));
typedef float f32x4 __attribute__((ext_vector_type(4)));
typedef unsigned int u32x4 __attribute__((ext_vector_type(4)));
typedef unsigned short u16x4 __attribute__((ext_vector_type(4)));
typedef unsigned short u16x8 __attribute__((ext_vector_type(8)));
typedef unsigned long long u64;

__device__ __forceinline__ unsigned short f2b(float f) {
    unsigned u = __builtin_bit_cast(unsigned, f);
    u += 0x7fffu + ((u >> 16) & 1u);
    return (unsigned short)(u >> 16);
}
__device__ __forceinline__ float b2f(unsigned short s) {
    unsigned u = ((unsigned)s) << 16;
    return __builtin_bit_cast(float, u);
}

// ---------- Kernel 1: xp = bf16( X[B*T,D] @ Wi[D,4H] ), fp32 accum ----------
// Same proven skeleton as rounds 0-9, scaled 64x64 -> 128x128 tile: 512 thr /
// 8 waves (2 m-tiles x 4 n-tiles), 8 MFMA per wave per K-iter (vs 4), 4x fewer
// blocks. Staging pattern and xp epilogue math unchanged.
__global__ __launch_bounds__(512) void xproj_gemm(const float* __restrict__ X,
                                                  const float* __restrict__ Wi,
                                                  unsigned short* __restrict__ xp)
{
    __shared__ unsigned short As[128][40];   // [m][k]
    __shared__ unsigned short Bs[128][40];   // [n][k] transposed
    const int nb = G4 / 128;
    const int m0 = (blockIdx.x / nb) * 128;
    const int n0 = (blockIdx.x % nb) * 128;
    const int tid = threadIdx.x;
    const int w = tid >> 6;
    const int lane = tid & 63;
    const int q = lane >> 4;
    const int l16 = lane & 15;
    const int wmRow = (w & 1) * 64;          // 2 m-tiles of 64 rows
    const int wn0 = (w >> 1) * 32;           // 4 n-tiles of 32 cols

    const int ar = tid >> 2, ac = (tid & 3) * 8;    // A: 128 rows x 32 k
    const int bk = tid >> 4, bn = (tid & 15) * 8;   // B: 32 k x 128 cols

    f32x4 acc[4][2] = {};

    for (int k0 = 0; k0 < DD; k0 += 32) {
        const float* ap = X + (size_t)(m0 + ar) * DD + k0 + ac;
        float4 a0 = *(const float4*)ap;
        float4 a1 = *(const float4*)(ap + 4);
        unsigned short* as = &As[ar][ac];
        as[0]=f2b(a0.x); as[1]=f2b(a0.y); as[2]=f2b(a0.z); as[3]=f2b(a0.w);
        as[4]=f2b(a1.x); as[5]=f2b(a1.y); as[6]=f2b(a1.z); as[7]=f2b(a1.w);
        const float* bp = Wi + (size_t)(k0 + bk) * G4 + n0 + bn;
        float4 b0 = *(const float4*)bp;
        float4 b1 = *(const float4*)(bp + 4);
        Bs[bn+0][bk]=f2b(b0.x); Bs[bn+1][bk]=f2b(b0.y); Bs[bn+2][bk]=f2b(b0.z); Bs[bn+3][bk]=f2b(b0.w);
        Bs[bn+4][bk]=f2b(b1.x); Bs[bn+5][bk]=f2b(b1.y); Bs[bn+6][bk]=f2b(b1.z); Bs[bn+7][bk]=f2b(b1.w);
        __syncthreads();
        bf16x8 af0 = *(const bf16x8*)&As[wmRow +  0 + l16][q*8];
        bf16x8 af1 = *(const bf16x8*)&As[wmRow + 16 + l16][q*8];
        bf16x8 af2 = *(const bf16x8*)&As[wmRow + 32 + l16][q*8];
        bf16x8 af3 = *(const bf16x8*)&As[wmRow + 48 + l16][q*8];
        bf16x8 bfr0 = *(const bf16x8*)&Bs[wn0 +  0 + l16][q*8];
        bf16x8 bfr1 = *(const bf16x8*)&Bs[wn0 + 16 + l16][q*8];
        acc[0][0] = __builtin_amdgcn_mfma_f32_16x16x32_bf16(af0, bfr0, acc[0][0], 0,0,0);
        acc[0][1] = __builtin_amdgcn_mfma_f32_16x16x32_bf16(af0, bfr1, acc[0][1], 0,0,0);
        acc[1][0] = __builtin_amdgcn_mfma_f32_16x16x32_bf16(af1, bfr0, acc[1][0], 0,0,0);
        acc[1][1] = __builtin_amdgcn_mfma_f32_16x16x32_bf16(af1, bfr1, acc[1][1], 0,0,0);
        acc[2][0] = __builtin_amdgcn_mfma_f32_16x16x32_bf16(af2, bfr0, acc[2][0], 0,0,0);
        acc[2][1] = __builtin_amdgcn_mfma_f32_16x16x32_bf16(af2, bfr1, acc[2][1], 0,0,0);
        acc[3][0] = __builtin_amdgcn_mfma_f32_16x16x32_bf16(af3, bfr0, acc[3][0], 0,0,0);
        acc[3][1] = __builtin_amdgcn_mfma_f32_16x16x32_bf16(af3, bfr1, acc[3][1], 0,0,0);
        __syncthreads();
    }
    #pragma unroll
    for (int i = 0; i < 4; i++)
        #pragma unroll
        for (int j = 0; j < 2; j++) {
            int R = m0 + wmRow + i*16 + q*4;
            int C = n0 + wn0 + j*16 + l16;
            int b = R >> 9;
            int t = R & 511;
            int g = C >> 10;
            int hd = C & (HH - 1);
            u16x4 v;
            v.x = f2b(acc[i][j][0]); v.y = f2b(acc[i][j][1]);
            v.z = f2b(acc[i][j][2]); v.w = f2b(acc[i][j][3]);
            size_t off = (((size_t)(b * HH + hd) * (TT/8) + (t >> 3)) * 4 + g) * 8 + (t & 7);
            *(u16x4*)(xp + off) = v;
        }
}

// ---------- Kernel 2: persistent LSTM scan, R1-BEST flag protocol (single phase) ----------
// Protocol scoreboard across passing rounds (us per rendezvous round):
//   R0 single-line RMW convoy + 64 pollers: 6.2 | R1 packed flags, plain
//   stores, wave0 wide-poll: 4.76 (BEST) | R3 padded flags, all-WG wide poll:
//   9.5 | R8 aggregator-epoch: 6.15 (extra chained hop).
// This round = R8's proven compute core + R1's proven best sync round applied
// to the single-phase step: producers plain-AGENT-store flags[wg] (PACKED
// 64-int array -> 2 cache lines), every WG's wave0 wide-polls all 64 directly.
// No RMW convoy, no aggregator indirection. XCD-local line abandoned after 5
// failures (sc0-only store->load visibility within an XCD unproven on gfx950).
__global__ __launch_bounds__(BLK, 1) void lstm_seq(
    const unsigned short* __restrict__ xp,      // [B][H][T/8][4][8] bf16
    const int* __restrict__ lengths,
    const float* __restrict__ c0,
    const float* __restrict__ h0,
    const float* __restrict__ Wh,
    const float* __restrict__ bias,
    float* __restrict__ out,                    // outputs[B,T,H] | c_fin[B,H] | h_fin[B,H]
    unsigned short* __restrict__ hbuf,          // [T+1][B*H] bf16 ring
    int* __restrict__ flags)                    // [64] PACKED, host memset 0xff (=-1)
{
    __shared__ float gs[2][32][65];          // [khalf][batch][gate*16+dim]
    const int wg = blockIdx.x;
    const int tid = threadIdx.x;
    const int lane = tid & 63;
    const int w = tid >> 6;                  // 0..7
    const int q = lane >> 4, l16 = lane & 15;

    const int Mt = (w & 1) * 16;             // batch tile
    const int kh = (w >> 1) & 1;             // K half
    const int cp = w >> 2;                   // col-tile pair: ct = cp*2 + cc
    const int kbase = kh * 512;

    // ---- one-time: load this wave's 32 Wh B-fragments into registers ----
    bf16x8 breg[16][2];
    #pragma unroll
    for (int kk = 0; kk < 16; ++kk) {
        #pragma unroll
        for (int cc = 0; cc < 2; ++cc) {
            const int col = (cp*2 + cc) * HH + wg * DPW + l16;
            const int kb = kbase + kk*32 + q*8;
            u16x8 tv;
            #pragma unroll
            for (int e = 0; e < 8; ++e)
                tv[e] = f2b(Wh[(size_t)(kb + e) * G4 + col]);
            breg[kk][cc] = __builtin_bit_cast(bf16x8, tv);
        }
    }

    const int bb = tid >> 4, dd = tid & 15;  // all 512 threads do pointwise
    const int gdim = wg * DPW + dd;
    float c   = c0[bb * HH + gdim];
    const int len = lengths[bb];
    const float bi  = bias[0*HH + gdim];
    const float bfg = bias[1*HH + gdim];
    const float bgv = bias[2*HH + gdim];
    const float bo  = bias[3*HH + gdim];
    const size_t xrow = ((size_t)bb * HH + gdim) * (TT/8) * 32;

    // h0 init: 128 threads store this WG's slice (32 b x 16 dims = 128 quads).
    if (tid < 128) {
        int b2 = tid >> 2, j = (tid & 3) * 4;
        const float* hp0 = h0 + (size_t)b2 * HH + wg * DPW + j;
        unsigned lo = (unsigned)f2b(hp0[0]) | ((unsigned)f2b(hp0[1]) << 16);
        unsigned hi = (unsigned)f2b(hp0[2]) | ((unsigned)f2b(hp0[3]) << 16);
        u64 v = (u64)lo | ((u64)hi << 32);
        __hip_atomic_store((u64*)(hbuf + (size_t)b2 * HH + wg * DPW + j), v,
                           __ATOMIC_RELAXED, __HIP_MEMORY_SCOPE_AGENT);
    }
    __syncthreads();                  // vmcnt(0): init stores acked at coherence point
    if (tid == 0)                     // publish slot 0 (plain store, no RMW)
        __hip_atomic_store(&flags[wg], 0, __ATOMIC_RELAXED, __HIP_MEMORY_SCOPE_AGENT);

    int fv = -1;                      // wave0 per-lane cached flag of WG 'lane'
    for (int t0 = 0; t0 < TT; t0 += 8) {
        // Prefetch 8 steps x 4 gates of x-projection: one contiguous 64B chunk.
        const unsigned short* xc = xp + xrow + (size_t)(t0 >> 3) * 32;
        u32x4 xq0 = __builtin_nontemporal_load((const u32x4*)(xc + 0));
        u32x4 xq1 = __builtin_nontemporal_load((const u32x4*)(xc + 8));
        u32x4 xq2 = __builtin_nontemporal_load((const u32x4*)(xc + 16));
        u32x4 xq3 = __builtin_nontemporal_load((const u32x4*)(xc + 24));
        float hreg[8];
        #pragma unroll
        for (int dt = 0; dt < 8; ++dt) {
            const int t = t0 + dt;
            // ---- R1-best poll: wave0 wide-gathers the packed 64-flag array ----
            if (w == 0) {
                int spins = 0;
                while (!__all(fv >= t)) {
                    fv = __hip_atomic_load(&flags[lane], __ATOMIC_RELAXED,
                                           __HIP_MEMORY_SCOPE_AGENT);
                    if (++spins > (1 << 20)) break;   // loud failure, never a hang
                }
            }
            __syncthreads();                                            // b1
            // ---- h slot t: plain cached loads (write-once slots; R0-proven) + MFMA ----
            const unsigned short* ha = hbuf + (size_t)t * HSLOT
                                     + (size_t)(Mt + l16) * HH + kbase + q*8;
            f32x4 acc0 = {0.f,0.f,0.f,0.f}, acc1 = {0.f,0.f,0.f,0.f};
            #pragma unroll
            for (int kk = 0; kk < 16; ++kk) {
                bf16x8 a = *(const bf16x8*)(ha + kk*32);
                acc0 = __builtin_amdgcn_mfma_f32_16x16x32_bf16(a, breg[kk][0], acc0, 0,0,0);
                acc1 = __builtin_amdgcn_mfma_f32_16x16x32_bf16(a, breg[kk][1], acc1, 0,0,0);
            }
            #pragma unroll
            for (int r = 0; r < 4; ++r) {
                gs[kh][Mt + q*4 + r][(cp*2+0)*16 + l16] = acc0[r];
                gs[kh][Mt + q*4 + r][(cp*2+1)*16 + l16] = acc1[r];
            }
            __syncthreads();                                            // b2
            // ---- pointwise (all 512 threads) ----
            const int wi = dt >> 1, sh = (dt & 1) * 16;
            float gi = gs[0][bb][ 0 + dd] + gs[1][bb][ 0 + dd] + b2f((unsigned short)(xq0[wi] >> sh)) + bi;
            float gf = gs[0][bb][16 + dd] + gs[1][bb][16 + dd] + b2f((unsigned short)(xq1[wi] >> sh)) + bfg;
            float gg = gs[0][bb][32 + dd] + gs[1][bb][32 + dd] + b2f((unsigned short)(xq2[wi] >> sh)) + bgv;
            float go = gs[0][bb][48 + dd] + gs[1][bb][48 + dd] + b2f((unsigned short)(xq3[wi] >> sh)) + bo;
            float si = 1.f / (1.f + __expf(-gi));
            float sf = 1.f / (1.f + __expf(-gf));
            float so = 1.f / (1.f + __expf(-go));
            float tg = 1.f - 2.f / (1.f + __expf(2.f * gg));
            c = sf * c + si * tg;
            float th = 1.f - 2.f / (1.f + __expf(2.f * c));
            float h = so * th;
            hreg[dt] = h;
            // Pack 4 bf16 h (dims 4-aligned) into u64 via shuffles; one store/quad.
            unsigned v = (unsigned)f2b(h);
            unsigned p1 = __shfl_xor(v, 1);
            unsigned pair = (dd & 1) ? (p1 | (v << 16)) : (v | (p1 << 16));
            unsigned p2 = __shfl_xor(pair, 2);
            u64 quad = (dd & 2) ? ((u64)p2 | ((u64)pair << 32))
                                : ((u64)pair | ((u64)p2 << 32));
            if ((dd & 3) == 0)
                __hip_atomic_store((u64*)(hbuf + (size_t)(t + 1) * HSLOT + (size_t)bb * HH + gdim),
                                   quad, __ATOMIC_RELAXED, __HIP_MEMORY_SCOPE_AGENT);
            if (t == len - 1) {       // rare: final states
                __builtin_nontemporal_store(c, &out[(size_t)BB*TT*HH + bb*HH + gdim]);
                __builtin_nontemporal_store(h, &out[(size_t)BB*TT*HH + (size_t)BB*HH + bb*HH + gdim]);
            }
            __syncthreads();          // b3: vmcnt(0) — h stores acked at coherence point
            if (tid == 0)             // publish slot t+1 (plain store, packed line)
                __hip_atomic_store(&flags[wg], t + 1,
                                   __ATOMIC_RELAXED, __HIP_MEMORY_SCOPE_AGENT);
            if (dt == 7) {
                // Flush 8 buffered h outputs AFTER the flag: HBM acks drain
                // during the next poll, off the critical path.
                #pragma unroll
                for (int j = 0; j < 8; ++j)
                    __builtin_nontemporal_store(hreg[j], &out[((size_t)bb * TT + t0 + j) * HH + gdim]);
            }
        }
    }
}

extern "C" void kernel_launch(void* const* d_in, const int* in_sizes, int n_in,
                              void* d_out, int out_size, void* d_ws, size_t ws_size,
                              hipStream_t stream)
{
    const float* X    = (const float*)d_in[0];
    const int*   lens = (const int*)d_in[1];
    const float* c0   = (const float*)d_in[2];
    const float* h0   = (const float*)d_in[3];
    const float* Wi   = (const float*)d_in[4];
    const float* Wh   = (const float*)d_in[5];
    const float* bias = (const float*)d_in[6];
    float* out = (float*)d_out;

    // ws layout: xp bf16 [B][H][T/8][4][8] (134.2 MB) | hbuf ring bf16 [T+1][B*H]
    //            (33.6 MB) | flags int[64] packed (256 B)
    unsigned short* xp   = (unsigned short*)d_ws;
    unsigned short* hbuf = xp + (size_t)BB * HH * TT * 4;
    int* flags = (int*)(hbuf + (size_t)(TT + 1) * HSLOT);

    // flags = -1: nobody passes the t=0 poll until h0 is published.
    (void)hipMemsetAsync(flags, 0xff, sizeof(int) * NWG, stream);

    xproj_gemm<<<dim3((BB*TT/128) * (G4/128)), dim3(512), 0, stream>>>(X, Wi, xp);

    const unsigned short* xp_c = xp;
    unsigned short* hbuf_p = hbuf;
    int* flags_p = flags;
    void* args[9];
    args[0] = (void*)&xp_c;
    args[1] = (void*)&lens;
    args[2] = (void*)&c0;
    args[3] = (void*)&h0;
    args[4] = (void*)&Wh;
    args[5] = (void*)&bias;
    args[6] = (void*)&out;
    args[7] = (void*)&hbuf_p;
    args[8] = (void*)&flags_p;
    (void)hipLaunchCooperativeKernel((void*)lstm_seq, dim3(NWG), dim3(BLK), args, 0, stream);
}